// Round 14
// baseline (372.476 us; speedup 1.0000x reference)
//
#include <hip/hip_runtime.h>
#include <stdint.h>

typedef float f32x4 __attribute__((ext_vector_type(4)));
typedef short bf16x8 __attribute__((ext_vector_type(8)));
typedef unsigned int u32x4 __attribute__((ext_vector_type(4)));
typedef unsigned short u16;
typedef unsigned int u32;

#define LDK 72           // GEMM LDS row stride (elems)
#define SCL2 0.1803368801111243f   // 0.125 * log2(e)

static __device__ __forceinline__ u16 f2bf(float f) {
  union { float f; u32 u; } x; x.f = f;
  return (u16)((x.u + 0x7FFFu + ((x.u >> 16) & 1u)) >> 16);  // RNE
}

static __device__ __forceinline__ u32 pk2(float lo, float hi) {
  u32 r;
  asm("v_cvt_pk_bf16_f32 %0, %1, %2" : "=v"(r) : "v"(lo), "v"(hi));
  return r;
}

static __device__ __forceinline__ f32x4 mma(bf16x8 a, bf16x8 b, f32x4 c) {
  return __builtin_amdgcn_mfma_f32_16x16x32_bf16(a, b, c, 0, 0, 0);
}

// ---------------- fused f32 -> bf16 convert of x, qkv_w, proj_w (dests contiguous in ws) ----------------
__global__ __launch_bounds__(256) void cvt_all(const float* __restrict__ x,
                                               const float* __restrict__ w1,
                                               const float* __restrict__ w2,
                                               u16* __restrict__ dst) {
  int i = blockIdx.x * blockDim.x + threadIdx.x;
  int stride = gridDim.x * blockDim.x;
  for (; i < 3145728; i += stride) {           // total float4 count (x 2097152 | w1 786432 | w2 262144)
    const float4* src;
    int off;
    if (i < 2097152)      { src = (const float4*)x;  off = i; }
    else if (i < 2883584) { src = (const float4*)w1; off = i - 2097152; }
    else                  { src = (const float4*)w2; off = i - 2883584; }
    float4 v = src[off];
    ushort4 o;
    o.x = f2bf(v.x); o.y = f2bf(v.y); o.z = f2bf(v.z); o.w = f2bf(v.w);
    ((ushort4*)dst)[i] = o;
  }
}

// ---------------- shared 128x128x(K=1024) bf16 GEMM core: C = A * B^T ----------------
// T14 issue-early/write-late staging (r12-proven correct; now with VGPR headroom from
// __launch_bounds__(256,2) on callers so ga/gb stay in registers instead of scratch).
static __device__ __forceinline__ void gemm128(const u16* __restrict__ A,
                                               const u16* __restrict__ Bmat,
                                               u16* lA, u16* lB,
                                               int bm, int bn, f32x4 (&acc)[4][4]) {
  const int t = threadIdx.x;
  const int lane = t & 63, wave = t >> 6;
  const int wr = wave >> 1, wc = wave & 1;
  const int g = lane >> 4, r16 = lane & 15;
  const int tr = t >> 3, tc8 = (t & 7) * 8;    // chunk i: row = i*32 + tr, col = tc8
  const u16* Ab = A + (bm + tr) * 1024 + tc8;
  const u16* Bb = Bmat + (bn + tr) * 1024 + tc8;

  uint4 ga[4], gb[4];
  #pragma unroll
  for (int i = 0; i < 4; i++) {                // prologue: tile kt=0
    ga[i] = *(const uint4*)(Ab + i * 32768);
    gb[i] = *(const uint4*)(Bb + i * 32768);
  }

  for (int kt = 0; kt < 1024; kt += 64) {
    __syncthreads();                           // all waves done reading previous tile
    #pragma unroll
    for (int i = 0; i < 4; i++) {              // write staged regs (load latency covered by prev compute)
      *(uint4*)(lA + (i * 32 + tr) * LDK + tc8) = ga[i];
      *(uint4*)(lB + (i * 32 + tr) * LDK + tc8) = gb[i];
    }
    __syncthreads();
    if (kt + 64 < 1024) {                      // T14: issue next-tile loads; compute covers latency
      #pragma unroll
      for (int i = 0; i < 4; i++) {
        ga[i] = *(const uint4*)(Ab + kt + 64 + i * 32768);
        gb[i] = *(const uint4*)(Bb + kt + 64 + i * 32768);
      }
    }
    #pragma unroll
    for (int kk = 0; kk < 2; kk++) {
      bf16x8 af[4], bfr[4];
      #pragma unroll
      for (int mi = 0; mi < 4; mi++)
        af[mi] = *(const bf16x8*)(lA + (wr * 64 + mi * 16 + r16) * LDK + kk * 32 + g * 8);
      #pragma unroll
      for (int nj = 0; nj < 4; nj++)
        bfr[nj] = *(const bf16x8*)(lB + (wc * 64 + nj * 16 + r16) * LDK + kk * 32 + g * 8);
      #pragma unroll
      for (int mi = 0; mi < 4; mi++)
        #pragma unroll
        for (int nj = 0; nj < 4; nj++)
          acc[mi][nj] = mma(af[mi], bfr[nj], acc[mi][nj]);
    }
  }
}

// ---------------- QKV projection + scatter to per-head Q,K,V^T (bf16) ----------------
__global__ __launch_bounds__(256, 2) void k_gemm_qkv(const u16* __restrict__ xb,
                                                     const u16* __restrict__ wb,
                                                     const float* __restrict__ qkv_b,
                                                     u16* __restrict__ Qs,
                                                     u16* __restrict__ Ks,
                                                     u16* __restrict__ Vt) {
  __shared__ __align__(16) u16 lds[2 * 128 * LDK];   // 36 KiB; reused for V transpose
  f32x4 acc[4][4] = {};
  // XCD-chunked swizzle: 1536 blocks -> 8 chunks of 16bm x 12bn
  int bid = blockIdx.y * 64 + blockIdx.x;
  int xcd = bid & 7, i0 = bid >> 3;
  int bx = (xcd >> 1) * 16 + i0 / 12;
  int by = (xcd & 1) * 12 + i0 % 12;
  const int bm = bx * 128, bn = by * 128;
  gemm128(xb, wb, lds, lds + 128 * LDK, bm, bn, acc);
  const int t = threadIdx.x, lane = t & 63, wave = t >> 6;
  const int wr = wave >> 1, wc = wave & 1;
  const int g = lane >> 4, r16 = lane & 15;
  if (bn < 2048) {
    // Q/K blocks
    #pragma unroll
    for (int nj = 0; nj < 4; nj++) {
      int f = bn + wc * 64 + nj * 16 + r16;
      float bias = qkv_b[f];
      int which = f >> 10;                      // 0=q 1=k
      int fl = f & 1023;
      int h = fl >> 6, dd = fl & 63;
      u16* base = which ? Ks : Qs;
      float scl = which ? 1.f : SCL2;
      #pragma unroll
      for (int mi = 0; mi < 4; mi++) {
        int mb = bm + wr * 64 + mi * 16 + g * 4;
        #pragma unroll
        for (int rg = 0; rg < 4; rg++) {
          int m = mb + rg;
          int b = m >> 11, s = m & 2047;
          base[(((b * 16 + h) * 2048) + s) * 64 + dd] = f2bf((acc[mi][nj][rg] + bias) * scl);
        }
      }
    }
  } else {
    // V blocks: transpose via LDS, then coalesced uint4 stores into Vt[dv][s]
    __syncthreads();
    #pragma unroll
    for (int nj = 0; nj < 4; nj++) {
      int fl = wc * 64 + nj * 16 + r16;         // 0..127
      float bias = qkv_b[bn + fl];
      #pragma unroll
      for (int mi = 0; mi < 4; mi++) {
        int ml = wr * 64 + mi * 16 + g * 4;
        *(u32*)(lds + fl * 144 + ml)     = pk2(acc[mi][nj][0] + bias, acc[mi][nj][1] + bias);
        *(u32*)(lds + fl * 144 + ml + 2) = pk2(acc[mi][nj][2] + bias, acc[mi][nj][3] + bias);
      }
    }
    __syncthreads();
    int b = bm >> 11, s0 = bm & 2047;
    #pragma unroll
    for (int i = 0; i < 8; i++) {
      int fl = i * 16 + (t >> 4);
      int m8 = (t & 15) * 8;
      uint4 val = *(uint4*)(lds + fl * 144 + m8);
      int f = bn + fl - 2048;
      int h = f >> 6, dd = f & 63;
      *(uint4*)(Vt + (((b * 16 + h) * 64) + dd) * 2048 + s0 + m8) = val;
    }
  }
}

// ---------------- flash attention v9 (VERIFIED) + XCD-owned-bh block swizzle ----------------
__global__ __launch_bounds__(256, 3) void k_attn(const u16* __restrict__ Qs,
                                                 const u16* __restrict__ Ks,
                                                 const u16* __restrict__ Vt,
                                                 u16* __restrict__ ctx) {
  __shared__ __align__(16) u16 lKs[2][64 * 64];   // swizzled K tiles, 8 KiB each
  __shared__ __align__(16) u16 lVs[2][64 * 72];   // permuted V tiles [dv][key-pos], 9 KiB each
  // flat 1024 blocks; XCD x owns lin [x*128, x*128+128) = bh x*8..x*8+7 (all 16 qt each)
  int bid = blockIdx.x;
  int lin = (bid & 7) * 128 + (bid >> 3);
  const int bh = lin >> 4, qt = lin & 15;
  const int b = bh >> 4, h = bh & 15;
  const u16* Qb = Qs + bh * (2048 * 64);
  const u16* Kb = Ks + bh * (2048 * 64);
  const u16* Vb = Vt + bh * (64 * 2048);
  const int t = threadIdx.x, lane = t & 63, wave = t >> 6;
  const int g = lane >> 4, r16 = lane & 15;
  const int q0 = qt * 128 + wave * 32;

  // Q fragments (B-operand of swapped QK^T), k = kk*32 + g*8 + i
  bf16x8 qf[2][2];
  #pragma unroll
  for (int j = 0; j < 2; j++)
    #pragma unroll
    for (int kk = 0; kk < 2; kk++)
      qf[j][kk] = *(const bf16x8*)(Qb + (q0 + j * 16 + r16) * 64 + kk * 32 + g * 8);

  u32x4 onesw;
  onesw.x = 0x3F803F80u; onesw.y = 0x3F803F80u; onesw.z = 0x3F803F80u; onesw.w = 0x3F803F80u;
  const bf16x8 ones = __builtin_bit_cast(bf16x8, onesw);

  f32x4 o[2][4] = {};
  f32x4 lsum[2] = {};
  const f32x4 INIT4 = {-4.f, -4.f, -4.f, -4.f};  // fixed softmax max (log2), cancels in ratio

  // staging offsets (2 chunks of 16B per thread for each of K and V)
  int kOffG[2], kOffL[2], vOffG[2], vOffL[2];
  #pragma unroll
  for (int i = 0; i < 2; i++) {
    int ci = i * 256 + t;
    int rK = ci >> 3, cK = ci & 7;
    kOffG[i] = rK * 64 + cK * 8;
    kOffL[i] = rK * 64 + ((cK ^ (rK & 7)) * 8);
    int rV = ci >> 3, c8 = ci & 7;
    int kb = c8 >> 2, cc = c8 & 3;
    vOffG[i] = rV * 2048 + c8 * 8;
    // key kb*32 + 16h+4a+b  ->  pos kb*32 + 8a+4h+b  (matches PV A-operand element order)
    vOffL[i] = rV * 72 + kb * 32 + 16 * (cc & 1) + 4 * (cc >> 1);
  }

  uint4 gk[2], gv[2];
  #pragma unroll
  for (int i = 0; i < 2; i++) gk[i] = *(const uint4*)(Kb + kOffG[i]);
  #pragma unroll
  for (int i = 0; i < 2; i++) gv[i] = *(const uint4*)(Vb + vOffG[i]);
  #pragma unroll
  for (int i = 0; i < 2; i++) *(uint4*)(&lKs[0][kOffL[i]]) = gk[i];
  #pragma unroll
  for (int i = 0; i < 2; i++) {
    uint2 lo; lo.x = gv[i].x; lo.y = gv[i].y;
    uint2 hi; hi.x = gv[i].z; hi.y = gv[i].w;
    *(uint2*)(&lVs[0][vOffL[i]]) = lo;
    *(uint2*)(&lVs[0][vOffL[i] + 8]) = hi;
  }
  __syncthreads();

  for (int tt = 0; tt < 32; ++tt) {
    const u16* lKc = lKs[tt & 1];
    const u16* lVc = lVs[tt & 1];
    if (tt < 31) {   // T14: issue next-tile global loads before compute
      #pragma unroll
      for (int i = 0; i < 2; i++) gk[i] = *(const uint4*)(Kb + (tt + 1) * 4096 + kOffG[i]);
      #pragma unroll
      for (int i = 0; i < 2; i++) gv[i] = *(const uint4*)(Vb + (tt + 1) * 64 + vOffG[i]);
    }
    __builtin_amdgcn_s_setprio(1);
    #pragma unroll
    for (int kb = 0; kb < 2; kb++) {
      const int sw = r16 & 7;
      const u16* kp0 = lKc + (kb * 32 + r16) * 64;
      const u16* kp1 = lKc + (kb * 32 + 16 + r16) * 64;
      bf16x8 kf00 = *(const bf16x8*)(kp0 + ((g ^ sw) * 8));
      bf16x8 kf01 = *(const bf16x8*)(kp0 + (((4 + g) ^ sw) * 8));
      bf16x8 kf10 = *(const bf16x8*)(kp1 + ((g ^ sw) * 8));
      bf16x8 kf11 = *(const bf16x8*)(kp1 + (((4 + g) ^ sw) * 8));
      bf16x8 vf[4];
      #pragma unroll
      for (int tdv = 0; tdv < 4; tdv++)
        vf[tdv] = *(const bf16x8*)(lVc + (tdv * 16 + r16) * 72 + kb * 32 + g * 8);
      #pragma unroll
      for (int j = 0; j < 2; j++) {
        f32x4 z0 = mma(kf00, qf[j][0], INIT4);
        z0 = mma(kf01, qf[j][1], z0);
        f32x4 z1 = mma(kf10, qf[j][0], INIT4);
        z1 = mma(kf11, qf[j][1], z1);
        float e0 = __builtin_amdgcn_exp2f(z0[0]), e1 = __builtin_amdgcn_exp2f(z0[1]);
        float e2 = __builtin_amdgcn_exp2f(z0[2]), e3 = __builtin_amdgcn_exp2f(z0[3]);
        float e4 = __builtin_amdgcn_exp2f(z1[0]), e5 = __builtin_amdgcn_exp2f(z1[1]);
        float e6 = __builtin_amdgcn_exp2f(z1[2]), e7 = __builtin_amdgcn_exp2f(z1[3]);
        u32x4 w_;
        w_.x = pk2(e0, e1); w_.y = pk2(e2, e3);
        w_.z = pk2(e4, e5); w_.w = pk2(e6, e7);
        bf16x8 pa = __builtin_bit_cast(bf16x8, w_);
        #pragma unroll
        for (int tdv = 0; tdv < 4; tdv++)
          o[j][tdv] = mma(pa, vf[tdv], o[j][tdv]);
        lsum[j] = mma(pa, ones, lsum[j]);
      }
    }
    __builtin_amdgcn_s_setprio(0);
    if (tt < 31) {   // write tile tt+1 into the other buffer (no reader conflict)
      u16* lKn = lKs[(tt + 1) & 1];
      u16* lVn = lVs[(tt + 1) & 1];
      #pragma unroll
      for (int i = 0; i < 2; i++) *(uint4*)(&lKn[kOffL[i]]) = gk[i];
      #pragma unroll
      for (int i = 0; i < 2; i++) {
        uint2 lo; lo.x = gv[i].x; lo.y = gv[i].y;
        uint2 hi; hi.x = gv[i].z; hi.y = gv[i].w;
        *(uint2*)(&lVn[vOffL[i]]) = lo;
        *(uint2*)(&lVn[vOffL[i] + 8]) = hi;
      }
    }
    __syncthreads();
  }

  #pragma unroll
  for (int j = 0; j < 2; j++) {
    f32x4 li;
    #pragma unroll
    for (int rg = 0; rg < 4; rg++) li[rg] = 1.0f / lsum[j][rg];
    #pragma unroll
    for (int tdv = 0; tdv < 4; tdv++)
      #pragma unroll
      for (int rg = 0; rg < 4; rg++) {
        int s = q0 + j * 16 + g * 4 + rg;
        ctx[((b * 2048 + s) * 1024) + h * 64 + tdv * 16 + r16] = f2bf(o[j][tdv][rg] * li[rg]);
      }
  }
}

// ---------------- output projection ----------------
__global__ __launch_bounds__(256, 2) void k_gemm_proj(const u16* __restrict__ ctx,
                                                      const u16* __restrict__ pwb,
                                                      const float* __restrict__ pb,
                                                      float* __restrict__ out) {
  __shared__ __align__(16) u16 lds[2 * 128 * LDK];
  f32x4 acc[4][4] = {};
  // XCD-chunked swizzle: 512 blocks -> 8 chunks of 8bm x 8bn
  int bid = blockIdx.y * 64 + blockIdx.x;
  int xcd = bid & 7, i0 = bid >> 3;
  int bx = xcd * 8 + (i0 >> 3);
  int by = i0 & 7;
  const int bm = bx * 128, bn = by * 128;
  gemm128(ctx, pwb, lds, lds + 128 * LDK, bm, bn, acc);
  const int lane = threadIdx.x & 63, wave = threadIdx.x >> 6;
  const int wr = wave >> 1, wc = wave & 1;
  const int g = lane >> 4, r16 = lane & 15;
  #pragma unroll
  for (int nj = 0; nj < 4; nj++) {
    int col = bn + wc * 64 + nj * 16 + r16;
    float bias = pb[col];
    #pragma unroll
    for (int mi = 0; mi < 4; mi++) {
      int mb = bm + wr * 64 + mi * 16 + g * 4;
      #pragma unroll
      for (int rg = 0; rg < 4; rg++)
        out[(mb + rg) * 1024 + col] = acc[mi][nj][rg] + bias;
    }
  }
}

extern "C" void kernel_launch(void* const* d_in, const int* in_sizes, int n_in,
                              void* d_out, int out_size, void* d_ws, size_t ws_size,
                              hipStream_t stream) {
  const float* x      = (const float*)d_in[0];
  const float* qkv_w  = (const float*)d_in[1];
  const float* qkv_b  = (const float*)d_in[2];
  const float* proj_w = (const float*)d_in[3];
  const float* proj_b = (const float*)d_in[4];
  float* out = (float*)d_out;
  char* ws = (char*)d_ws;

  u16* xb  = (u16*)(ws);                 // [8192][1024]
  u16* wb  = (u16*)(ws + 16777216);      // [3072][1024]
  u16* pwb = (u16*)(ws + 23068672);      // [1024][1024]
  u16* Qs  = (u16*)(ws + 25165824);      // Q*SCL2      [64][2048][64]
  u16* Ks  = (u16*)(ws + 41943040);      // K           [64][2048][64]
  u16* Vt  = (u16*)(ws + 58720256);      // V^T         [64][64][2048]
  u16* ctx = (u16*)(ws + 75497472);      // attn out    [8192][1024]

  cvt_all<<<2048, 256, 0, stream>>>(x, qkv_w, proj_w, (u16*)ws);
  k_gemm_qkv<<<dim3(64, 24), 256, 0, stream>>>(xb, wb, qkv_b, Qs, Ks, Vt);
  k_attn<<<1024, 256, 0, stream>>>(Qs, Ks, Vt, ctx);
  k_gemm_proj<<<dim3(64, 8), 256, 0, stream>>>(ctx, pwb, proj_b, out);
}

// Round 15
// 183.236 us; speedup vs baseline: 2.0328x; 2.0328x over previous
//
#include <hip/hip_runtime.h>
#include <stdint.h>

typedef float f32x4 __attribute__((ext_vector_type(4)));
typedef short bf16x8 __attribute__((ext_vector_type(8)));
typedef unsigned int u32x4 __attribute__((ext_vector_type(4)));
typedef unsigned short u16;
typedef unsigned int u32;

#define LDK 72           // GEMM LDS row stride (elems)
#define SCL2 0.1803368801111243f   // 0.125 * log2(e)

static __device__ __forceinline__ u16 f2bf(float f) {
  union { float f; u32 u; } x; x.f = f;
  return (u16)((x.u + 0x7FFFu + ((x.u >> 16) & 1u)) >> 16);  // RNE
}

static __device__ __forceinline__ u32 pk2(float lo, float hi) {
  u32 r;
  asm("v_cvt_pk_bf16_f32 %0, %1, %2" : "=v"(r) : "v"(lo), "v"(hi));
  return r;
}

static __device__ __forceinline__ f32x4 mma(bf16x8 a, bf16x8 b, f32x4 c) {
  return __builtin_amdgcn_mfma_f32_16x16x32_bf16(a, b, c, 0, 0, 0);
}

// ---------------- fused f32 -> bf16 convert of x, qkv_w, proj_w (dests contiguous in ws) ----------------
__global__ __launch_bounds__(256) void cvt_all(const float* __restrict__ x,
                                               const float* __restrict__ w1,
                                               const float* __restrict__ w2,
                                               u16* __restrict__ dst) {
  int i = blockIdx.x * blockDim.x + threadIdx.x;
  int stride = gridDim.x * blockDim.x;
  for (; i < 3145728; i += stride) {           // total float4 count (x 2097152 | w1 786432 | w2 262144)
    const float4* src;
    int off;
    if (i < 2097152)      { src = (const float4*)x;  off = i; }
    else if (i < 2883584) { src = (const float4*)w1; off = i - 2097152; }
    else                  { src = (const float4*)w2; off = i - 2883584; }
    float4 v = src[off];
    ushort4 o;
    o.x = f2bf(v.x); o.y = f2bf(v.y); o.z = f2bf(v.z); o.w = f2bf(v.w);
    ((ushort4*)dst)[i] = o;
  }
}

// ---------------- shared 128x128x(K=1024) bf16 GEMM core: C = A * B^T (r1-PROVEN form) ----------------
static __device__ __forceinline__ void gemm128(const u16* __restrict__ A,
                                               const u16* __restrict__ Bmat,
                                               u16* lA, u16* lB,
                                               int bm, int bn, f32x4 (&acc)[4][4]) {
  const int t = threadIdx.x;
  const int lane = t & 63, wave = t >> 6;
  const int wr = wave >> 1, wc = wave & 1;
  const int g = lane >> 4, r16 = lane & 15;
  for (int kt = 0; kt < 1024; kt += 64) {
    __syncthreads();
    #pragma unroll
    for (int i = 0; i < 4; i++) {
      int ci = i * 256 + t;
      int r = ci >> 3, c = (ci & 7) * 8;
      *(uint4*)(lA + r * LDK + c) = *(const uint4*)(A + (bm + r) * 1024 + kt + c);
      *(uint4*)(lB + r * LDK + c) = *(const uint4*)(Bmat + (bn + r) * 1024 + kt + c);
    }
    __syncthreads();
    #pragma unroll
    for (int kk = 0; kk < 2; kk++) {
      bf16x8 af[4], bfr[4];
      #pragma unroll
      for (int mi = 0; mi < 4; mi++)
        af[mi] = *(const bf16x8*)(lA + (wr * 64 + mi * 16 + r16) * LDK + kk * 32 + g * 8);
      #pragma unroll
      for (int nj = 0; nj < 4; nj++)
        bfr[nj] = *(const bf16x8*)(lB + (wc * 64 + nj * 16 + r16) * LDK + kk * 32 + g * 8);
      #pragma unroll
      for (int mi = 0; mi < 4; mi++)
        #pragma unroll
        for (int nj = 0; nj < 4; nj++)
          acc[mi][nj] = mma(af[mi], bfr[nj], acc[mi][nj]);
    }
  }
}

// ---------------- QKV projection + scatter to per-head Q,K,V^T (bf16) ----------------
__global__ __launch_bounds__(256) void k_gemm_qkv(const u16* __restrict__ xb,
                                                  const u16* __restrict__ wb,
                                                  const float* __restrict__ qkv_b,
                                                  u16* __restrict__ Qs,
                                                  u16* __restrict__ Ks,
                                                  u16* __restrict__ Vt) {
  __shared__ __align__(16) u16 lds[2 * 128 * LDK];   // 36 KiB; reused for V transpose
  f32x4 acc[4][4] = {};
  // XCD-chunked swizzle: 1536 blocks -> 8 chunks of 16bm x 12bn
  int bid = blockIdx.y * 64 + blockIdx.x;
  int xcd = bid & 7, i0 = bid >> 3;
  int bx = (xcd >> 1) * 16 + i0 / 12;
  int by = (xcd & 1) * 12 + i0 % 12;
  const int bm = bx * 128, bn = by * 128;
  gemm128(xb, wb, lds, lds + 128 * LDK, bm, bn, acc);
  const int t = threadIdx.x, lane = t & 63, wave = t >> 6;
  const int wr = wave >> 1, wc = wave & 1;
  const int g = lane >> 4, r16 = lane & 15;
  if (bn < 2048) {
    // Q/K blocks
    #pragma unroll
    for (int nj = 0; nj < 4; nj++) {
      int f = bn + wc * 64 + nj * 16 + r16;
      float bias = qkv_b[f];
      int which = f >> 10;                      // 0=q 1=k
      int fl = f & 1023;
      int h = fl >> 6, dd = fl & 63;
      u16* base = which ? Ks : Qs;
      float scl = which ? 1.f : SCL2;
      #pragma unroll
      for (int mi = 0; mi < 4; mi++) {
        int mb = bm + wr * 64 + mi * 16 + g * 4;
        #pragma unroll
        for (int rg = 0; rg < 4; rg++) {
          int m = mb + rg;
          int b = m >> 11, s = m & 2047;
          base[(((b * 16 + h) * 2048) + s) * 64 + dd] = f2bf((acc[mi][nj][rg] + bias) * scl);
        }
      }
    }
  } else {
    // V blocks: transpose via LDS, then coalesced uint4 stores into Vt[dv][s]
    __syncthreads();
    #pragma unroll
    for (int nj = 0; nj < 4; nj++) {
      int fl = wc * 64 + nj * 16 + r16;         // 0..127
      float bias = qkv_b[bn + fl];
      #pragma unroll
      for (int mi = 0; mi < 4; mi++) {
        int ml = wr * 64 + mi * 16 + g * 4;
        *(u32*)(lds + fl * 144 + ml)     = pk2(acc[mi][nj][0] + bias, acc[mi][nj][1] + bias);
        *(u32*)(lds + fl * 144 + ml + 2) = pk2(acc[mi][nj][2] + bias, acc[mi][nj][3] + bias);
      }
    }
    __syncthreads();
    int b = bm >> 11, s0 = bm & 2047;
    #pragma unroll
    for (int i = 0; i < 8; i++) {
      int fl = i * 16 + (t >> 4);
      int m8 = (t & 15) * 8;
      uint4 val = *(uint4*)(lds + fl * 144 + m8);
      int f = bn + fl - 2048;
      int h = f >> 6, dd = f & 63;
      *(uint4*)(Vt + (((b * 16 + h) * 64) + dd) * 2048 + s0 + m8) = val;
    }
  }
}

// ---------------- flash attention v9 + XCD swizzle; 4 blocks/CU (tail fix) ----------------
__global__ __launch_bounds__(256, 4) void k_attn(const u16* __restrict__ Qs,
                                                 const u16* __restrict__ Ks,
                                                 const u16* __restrict__ Vt,
                                                 u16* __restrict__ ctx) {
  __shared__ __align__(16) u16 lKs[2][64 * 64];   // swizzled K tiles, 8 KiB each
  __shared__ __align__(16) u16 lVs[2][64 * 72];   // permuted V tiles [dv][key-pos], 9 KiB each
  // flat 1024 blocks; XCD x owns lin [x*128, x*128+128) = bh x*8..x*8+7 (all 16 qt each)
  int bid = blockIdx.x;
  int lin = (bid & 7) * 128 + (bid >> 3);
  const int bh = lin >> 4, qt = lin & 15;
  const int b = bh >> 4, h = bh & 15;
  const u16* Qb = Qs + bh * (2048 * 64);
  const u16* Kb = Ks + bh * (2048 * 64);
  const u16* Vb = Vt + bh * (64 * 2048);
  const int t = threadIdx.x, lane = t & 63, wave = t >> 6;
  const int g = lane >> 4, r16 = lane & 15;
  const int q0 = qt * 128 + wave * 32;

  // Q fragments (B-operand of swapped QK^T), k = kk*32 + g*8 + i
  bf16x8 qf[2][2];
  #pragma unroll
  for (int j = 0; j < 2; j++)
    #pragma unroll
    for (int kk = 0; kk < 2; kk++)
      qf[j][kk] = *(const bf16x8*)(Qb + (q0 + j * 16 + r16) * 64 + kk * 32 + g * 8);

  u32x4 onesw;
  onesw.x = 0x3F803F80u; onesw.y = 0x3F803F80u; onesw.z = 0x3F803F80u; onesw.w = 0x3F803F80u;
  const bf16x8 ones = __builtin_bit_cast(bf16x8, onesw);

  f32x4 o[2][4] = {};
  f32x4 lsum[2] = {};
  const f32x4 INIT4 = {-4.f, -4.f, -4.f, -4.f};  // fixed softmax max (log2), cancels in ratio

  // staging offsets (2 chunks of 16B per thread for each of K and V)
  int kOffG[2], kOffL[2], vOffG[2], vOffL[2];
  #pragma unroll
  for (int i = 0; i < 2; i++) {
    int ci = i * 256 + t;
    int rK = ci >> 3, cK = ci & 7;
    kOffG[i] = rK * 64 + cK * 8;
    kOffL[i] = rK * 64 + ((cK ^ (rK & 7)) * 8);
    int rV = ci >> 3, c8 = ci & 7;
    int kb = c8 >> 2, cc = c8 & 3;
    vOffG[i] = rV * 2048 + c8 * 8;
    // key kb*32 + 16h+4a+b  ->  pos kb*32 + 8a+4h+b  (matches PV A-operand element order)
    vOffL[i] = rV * 72 + kb * 32 + 16 * (cc & 1) + 4 * (cc >> 1);
  }

  uint4 gk[2], gv[2];
  #pragma unroll
  for (int i = 0; i < 2; i++) gk[i] = *(const uint4*)(Kb + kOffG[i]);
  #pragma unroll
  for (int i = 0; i < 2; i++) gv[i] = *(const uint4*)(Vb + vOffG[i]);
  #pragma unroll
  for (int i = 0; i < 2; i++) *(uint4*)(&lKs[0][kOffL[i]]) = gk[i];
  #pragma unroll
  for (int i = 0; i < 2; i++) {
    uint2 lo; lo.x = gv[i].x; lo.y = gv[i].y;
    uint2 hi; hi.x = gv[i].z; hi.y = gv[i].w;
    *(uint2*)(&lVs[0][vOffL[i]]) = lo;
    *(uint2*)(&lVs[0][vOffL[i] + 8]) = hi;
  }
  __syncthreads();

  for (int tt = 0; tt < 32; ++tt) {
    const u16* lKc = lKs[tt & 1];
    const u16* lVc = lVs[tt & 1];
    if (tt < 31) {   // T14: issue next-tile global loads before compute
      #pragma unroll
      for (int i = 0; i < 2; i++) gk[i] = *(const uint4*)(Kb + (tt + 1) * 4096 + kOffG[i]);
      #pragma unroll
      for (int i = 0; i < 2; i++) gv[i] = *(const uint4*)(Vb + (tt + 1) * 64 + vOffG[i]);
    }
    __builtin_amdgcn_s_setprio(1);
    #pragma unroll
    for (int kb = 0; kb < 2; kb++) {
      const int sw = r16 & 7;
      const u16* kp0 = lKc + (kb * 32 + r16) * 64;
      const u16* kp1 = lKc + (kb * 32 + 16 + r16) * 64;
      bf16x8 kf00 = *(const bf16x8*)(kp0 + ((g ^ sw) * 8));
      bf16x8 kf01 = *(const bf16x8*)(kp0 + (((4 + g) ^ sw) * 8));
      bf16x8 kf10 = *(const bf16x8*)(kp1 + ((g ^ sw) * 8));
      bf16x8 kf11 = *(const bf16x8*)(kp1 + (((4 + g) ^ sw) * 8));
      bf16x8 vf[4];
      #pragma unroll
      for (int tdv = 0; tdv < 4; tdv++)
        vf[tdv] = *(const bf16x8*)(lVc + (tdv * 16 + r16) * 72 + kb * 32 + g * 8);
      #pragma unroll
      for (int j = 0; j < 2; j++) {
        f32x4 z0 = mma(kf00, qf[j][0], INIT4);
        z0 = mma(kf01, qf[j][1], z0);
        f32x4 z1 = mma(kf10, qf[j][0], INIT4);
        z1 = mma(kf11, qf[j][1], z1);
        float e0 = __builtin_amdgcn_exp2f(z0[0]), e1 = __builtin_amdgcn_exp2f(z0[1]);
        float e2 = __builtin_amdgcn_exp2f(z0[2]), e3 = __builtin_amdgcn_exp2f(z0[3]);
        float e4 = __builtin_amdgcn_exp2f(z1[0]), e5 = __builtin_amdgcn_exp2f(z1[1]);
        float e6 = __builtin_amdgcn_exp2f(z1[2]), e7 = __builtin_amdgcn_exp2f(z1[3]);
        u32x4 w_;
        w_.x = pk2(e0, e1); w_.y = pk2(e2, e3);
        w_.z = pk2(e4, e5); w_.w = pk2(e6, e7);
        bf16x8 pa = __builtin_bit_cast(bf16x8, w_);
        #pragma unroll
        for (int tdv = 0; tdv < 4; tdv++)
          o[j][tdv] = mma(pa, vf[tdv], o[j][tdv]);
        lsum[j] = mma(pa, ones, lsum[j]);
      }
    }
    __builtin_amdgcn_s_setprio(0);
    if (tt < 31) {   // write tile tt+1 into the other buffer (no reader conflict)
      u16* lKn = lKs[(tt + 1) & 1];
      u16* lVn = lVs[(tt + 1) & 1];
      #pragma unroll
      for (int i = 0; i < 2; i++) *(uint4*)(&lKn[kOffL[i]]) = gk[i];
      #pragma unroll
      for (int i = 0; i < 2; i++) {
        uint2 lo; lo.x = gv[i].x; lo.y = gv[i].y;
        uint2 hi; hi.x = gv[i].z; hi.y = gv[i].w;
        *(uint2*)(&lVn[vOffL[i]]) = lo;
        *(uint2*)(&lVn[vOffL[i] + 8]) = hi;
      }
    }
    __syncthreads();
  }

  #pragma unroll
  for (int j = 0; j < 2; j++) {
    f32x4 li;
    #pragma unroll
    for (int rg = 0; rg < 4; rg++) li[rg] = 1.0f / lsum[j][rg];
    #pragma unroll
    for (int tdv = 0; tdv < 4; tdv++)
      #pragma unroll
      for (int rg = 0; rg < 4; rg++) {
        int s = q0 + j * 16 + g * 4 + rg;
        ctx[((b * 2048 + s) * 1024) + h * 64 + tdv * 16 + r16] = f2bf(o[j][tdv][rg] * li[rg]);
      }
  }
}

// ---------------- output projection ----------------
__global__ __launch_bounds__(256) void k_gemm_proj(const u16* __restrict__ ctx,
                                                   const u16* __restrict__ pwb,
                                                   const float* __restrict__ pb,
                                                   float* __restrict__ out) {
  __shared__ __align__(16) u16 lds[2 * 128 * LDK];
  f32x4 acc[4][4] = {};
  // XCD-chunked swizzle: 512 blocks -> 8 chunks of 8bm x 8bn
  int bid = blockIdx.y * 64 + blockIdx.x;
  int xcd = bid & 7, i0 = bid >> 3;
  int bx = xcd * 8 + (i0 >> 3);
  int by = i0 & 7;
  const int bm = bx * 128, bn = by * 128;
  gemm128(ctx, pwb, lds, lds + 128 * LDK, bm, bn, acc);
  const int lane = threadIdx.x & 63, wave = threadIdx.x >> 6;
  const int wr = wave >> 1, wc = wave & 1;
  const int g = lane >> 4, r16 = lane & 15;
  #pragma unroll
  for (int nj = 0; nj < 4; nj++) {
    int col = bn + wc * 64 + nj * 16 + r16;
    float bias = pb[col];
    #pragma unroll
    for (int mi = 0; mi < 4; mi++) {
      int mb = bm + wr * 64 + mi * 16 + g * 4;
      #pragma unroll
      for (int rg = 0; rg < 4; rg++)
        out[(mb + rg) * 1024 + col] = acc[mi][nj][rg] + bias;
    }
  }
}

extern "C" void kernel_launch(void* const* d_in, const int* in_sizes, int n_in,
                              void* d_out, int out_size, void* d_ws, size_t ws_size,
                              hipStream_t stream) {
  const float* x      = (const float*)d_in[0];
  const float* qkv_w  = (const float*)d_in[1];
  const float* qkv_b  = (const float*)d_in[2];
  const float* proj_w = (const float*)d_in[3];
  const float* proj_b = (const float*)d_in[4];
  float* out = (float*)d_out;
  char* ws = (char*)d_ws;

  u16* xb  = (u16*)(ws);                 // [8192][1024]
  u16* wb  = (u16*)(ws + 16777216);      // [3072][1024]
  u16* pwb = (u16*)(ws + 23068672);      // [1024][1024]
  u16* Qs  = (u16*)(ws + 25165824);      // Q*SCL2      [64][2048][64]
  u16* Ks  = (u16*)(ws + 41943040);      // K           [64][2048][64]
  u16* Vt  = (u16*)(ws + 58720256);      // V^T         [64][64][2048]
  u16* ctx = (u16*)(ws + 75497472);      // attn out    [8192][1024]

  cvt_all<<<2048, 256, 0, stream>>>(x, qkv_w, proj_w, (u16*)ws);
  k_gemm_qkv<<<dim3(64, 24), 256, 0, stream>>>(xb, wb, qkv_b, Qs, Ks, Vt);
  k_attn<<<1024, 256, 0, stream>>>(Qs, Ks, Vt, ctx);
  k_gemm_proj<<<dim3(64, 8), 256, 0, stream>>>(ctx, pwb, proj_b, out);
}

// Round 16
// 171.850 us; speedup vs baseline: 2.1675x; 1.0663x over previous
//
#include <hip/hip_runtime.h>
#include <stdint.h>

typedef float f32x4 __attribute__((ext_vector_type(4)));
typedef short bf16x8 __attribute__((ext_vector_type(8)));
typedef unsigned int u32x4 __attribute__((ext_vector_type(4)));
typedef unsigned short u16;
typedef unsigned int u32;

#define SCL2 0.1803368801111243f   // 0.125 * log2(e)

static __device__ __forceinline__ u16 f2bf(float f) {
  union { float f; u32 u; } x; x.f = f;
  return (u16)((x.u + 0x7FFFu + ((x.u >> 16) & 1u)) >> 16);  // RNE
}

static __device__ __forceinline__ u32 pk2(float lo, float hi) {
  u32 r;
  asm("v_cvt_pk_bf16_f32 %0, %1, %2" : "=v"(r) : "v"(lo), "v"(hi));
  return r;
}

static __device__ __forceinline__ f32x4 mma(bf16x8 a, bf16x8 b, f32x4 c) {
  return __builtin_amdgcn_mfma_f32_16x16x32_bf16(a, b, c, 0, 0, 0);
}

// async global->LDS DMA, 16B per lane; LDS dest is wave-uniform base + lane*16
static __device__ __forceinline__ void gl_lds16(const u16* g, u16* l) {
  __builtin_amdgcn_global_load_lds((const __attribute__((address_space(1))) void*)g,
                                   (__attribute__((address_space(3))) void*)l, 16, 0, 0);
}

// ---------------- fused f32 -> bf16 convert of x, qkv_w, proj_w (dests contiguous in ws) ----------------
__global__ __launch_bounds__(256) void cvt_all(const float* __restrict__ x,
                                               const float* __restrict__ w1,
                                               const float* __restrict__ w2,
                                               u16* __restrict__ dst) {
  int i = blockIdx.x * blockDim.x + threadIdx.x;
  int stride = gridDim.x * blockDim.x;
  for (; i < 3145728; i += stride) {           // total float4 count (x 2097152 | w1 786432 | w2 262144)
    const float4* src;
    int off;
    if (i < 2097152)      { src = (const float4*)x;  off = i; }
    else if (i < 2883584) { src = (const float4*)w1; off = i - 2097152; }
    else                  { src = (const float4*)w2; off = i - 2883584; }
    float4 v = src[off];
    ushort4 o;
    o.x = f2bf(v.x); o.y = f2bf(v.y); o.z = f2bf(v.z); o.w = f2bf(v.w);
    ((ushort4*)dst)[i] = o;
  }
}

// ---------------- shared 128x128x(K=1024) bf16 GEMM core: C = A * B^T ----------------
// m97-pattern staging: global_load_lds width=16 into LINEAR [128][64] LDS tiles, with
// pre-swizzled global source (srcChunk = c8 ^ (row&7)) and the same XOR on b128 frag reads.
// Fragment contents identical to the r1-proven gemm128.
static __device__ __forceinline__ void gemm128(const u16* __restrict__ A,
                                               const u16* __restrict__ Bmat,
                                               u16* lA, u16* lB,
                                               int bm, int bn, f32x4 (&acc)[4][4]) {
  const int t = threadIdx.x;
  const int lane = t & 63, wave = t >> 6;
  const int wr = wave >> 1, wc = wave & 1;
  const int g = lane >> 4, r16 = lane & 15;
  const int sw = r16 & 7;
  // staging geometry: call i covers rows i*32 + wave*8 + (lane>>3), src col chunk (lane&7)^(lane>>3)
  const int srow = wave * 8 + (lane >> 3);
  const int scol = ((lane & 7) ^ (lane >> 3)) * 8;
  const u16* As = A + (bm + srow) * 1024 + scol;
  const u16* Bs = Bmat + (bn + srow) * 1024 + scol;
  u16* const dA = lA + wave * 512;             // wave-uniform LDS base (elements)
  u16* const dB = lB + wave * 512;

  for (int kt = 0; kt < 1024; kt += 64) {
    __syncthreads();                           // all waves done reading previous tile
    #pragma unroll
    for (int i = 0; i < 4; i++) {              // 8 DMA issues/thread-visible-wave: 32KB total
      gl_lds16(As + kt + i * 32768, dA + i * 2048);
      gl_lds16(Bs + kt + i * 32768, dB + i * 2048);
    }
    __syncthreads();                           // compiler drains vmcnt(0) before this barrier
    #pragma unroll
    for (int kk = 0; kk < 2; kk++) {
      bf16x8 af[4], bfr[4];
      #pragma unroll
      for (int mi = 0; mi < 4; mi++)
        af[mi] = *(const bf16x8*)(lA + (wr * 64 + mi * 16 + r16) * 64 + (((kk * 4 + g) ^ sw) * 8));
      #pragma unroll
      for (int nj = 0; nj < 4; nj++)
        bfr[nj] = *(const bf16x8*)(lB + (wc * 64 + nj * 16 + r16) * 64 + (((kk * 4 + g) ^ sw) * 8));
      #pragma unroll
      for (int mi = 0; mi < 4; mi++)
        #pragma unroll
        for (int nj = 0; nj < 4; nj++)
          acc[mi][nj] = mma(af[mi], bfr[nj], acc[mi][nj]);
    }
  }
}

// ---------------- QKV projection + scatter to per-head Q,K,V^T (bf16) ----------------
__global__ __launch_bounds__(256) void k_gemm_qkv(const u16* __restrict__ xb,
                                                  const u16* __restrict__ wb,
                                                  const float* __restrict__ qkv_b,
                                                  u16* __restrict__ Qs,
                                                  u16* __restrict__ Ks,
                                                  u16* __restrict__ Vt) {
  __shared__ __align__(16) u16 lds[18432];     // GEMM: lA=lds[0..8191], lB=lds[8192..16383]; V-epi needs 18432
  f32x4 acc[4][4] = {};
  // XCD-chunked swizzle: 1536 blocks -> 8 chunks of 16bm x 12bn
  int bid = blockIdx.y * 64 + blockIdx.x;
  int xcd = bid & 7, i0 = bid >> 3;
  int bx = (xcd >> 1) * 16 + i0 / 12;
  int by = (xcd & 1) * 12 + i0 % 12;
  const int bm = bx * 128, bn = by * 128;
  gemm128(xb, wb, lds, lds + 8192, bm, bn, acc);
  const int t = threadIdx.x, lane = t & 63, wave = t >> 6;
  const int wr = wave >> 1, wc = wave & 1;
  const int g = lane >> 4, r16 = lane & 15;
  if (bn < 2048) {
    // Q/K blocks
    #pragma unroll
    for (int nj = 0; nj < 4; nj++) {
      int f = bn + wc * 64 + nj * 16 + r16;
      float bias = qkv_b[f];
      int which = f >> 10;                      // 0=q 1=k
      int fl = f & 1023;
      int h = fl >> 6, dd = fl & 63;
      u16* base = which ? Ks : Qs;
      float scl = which ? 1.f : SCL2;
      #pragma unroll
      for (int mi = 0; mi < 4; mi++) {
        int mb = bm + wr * 64 + mi * 16 + g * 4;
        #pragma unroll
        for (int rg = 0; rg < 4; rg++) {
          int m = mb + rg;
          int b = m >> 11, s = m & 2047;
          base[(((b * 16 + h) * 2048) + s) * 64 + dd] = f2bf((acc[mi][nj][rg] + bias) * scl);
        }
      }
    }
  } else {
    // V blocks: transpose via LDS, then coalesced uint4 stores into Vt[dv][s]
    __syncthreads();
    #pragma unroll
    for (int nj = 0; nj < 4; nj++) {
      int fl = wc * 64 + nj * 16 + r16;         // 0..127
      float bias = qkv_b[bn + fl];
      #pragma unroll
      for (int mi = 0; mi < 4; mi++) {
        int ml = wr * 64 + mi * 16 + g * 4;
        *(u32*)(lds + fl * 144 + ml)     = pk2(acc[mi][nj][0] + bias, acc[mi][nj][1] + bias);
        *(u32*)(lds + fl * 144 + ml + 2) = pk2(acc[mi][nj][2] + bias, acc[mi][nj][3] + bias);
      }
    }
    __syncthreads();
    int b = bm >> 11, s0 = bm & 2047;
    #pragma unroll
    for (int i = 0; i < 8; i++) {
      int fl = i * 16 + (t >> 4);
      int m8 = (t & 15) * 8;
      uint4 val = *(uint4*)(lds + fl * 144 + m8);
      int f = bn + fl - 2048;
      int h = f >> 6, dd = f & 63;
      *(uint4*)(Vt + (((b * 16 + h) * 64) + dd) * 2048 + s0 + m8) = val;
    }
  }
}

// ---------------- flash attention v9 + XCD swizzle; 4 blocks/CU ----------------
__global__ __launch_bounds__(256, 4) void k_attn(const u16* __restrict__ Qs,
                                                 const u16* __restrict__ Ks,
                                                 const u16* __restrict__ Vt,
                                                 u16* __restrict__ ctx) {
  __shared__ __align__(16) u16 lKs[2][64 * 64];   // swizzled K tiles, 8 KiB each
  __shared__ __align__(16) u16 lVs[2][64 * 72];   // permuted V tiles [dv][key-pos], 9 KiB each
  // flat 1024 blocks; XCD x owns lin [x*128, x*128+128) = bh x*8..x*8+7 (all 16 qt each)
  int bid = blockIdx.x;
  int lin = (bid & 7) * 128 + (bid >> 3);
  const int bh = lin >> 4, qt = lin & 15;
  const int b = bh >> 4, h = bh & 15;
  const u16* Qb = Qs + bh * (2048 * 64);
  const u16* Kb = Ks + bh * (2048 * 64);
  const u16* Vb = Vt + bh * (64 * 2048);
  const int t = threadIdx.x, lane = t & 63, wave = t >> 6;
  const int g = lane >> 4, r16 = lane & 15;
  const int q0 = qt * 128 + wave * 32;

  // Q fragments (B-operand of swapped QK^T), k = kk*32 + g*8 + i
  bf16x8 qf[2][2];
  #pragma unroll
  for (int j = 0; j < 2; j++)
    #pragma unroll
    for (int kk = 0; kk < 2; kk++)
      qf[j][kk] = *(const bf16x8*)(Qb + (q0 + j * 16 + r16) * 64 + kk * 32 + g * 8);

  u32x4 onesw;
  onesw.x = 0x3F803F80u; onesw.y = 0x3F803F80u; onesw.z = 0x3F803F80u; onesw.w = 0x3F803F80u;
  const bf16x8 ones = __builtin_bit_cast(bf16x8, onesw);

  f32x4 o[2][4] = {};
  f32x4 lsum[2] = {};
  const f32x4 INIT4 = {-4.f, -4.f, -4.f, -4.f};  // fixed softmax max (log2), cancels in ratio

  // staging offsets (2 chunks of 16B per thread for each of K and V)
  int kOffG[2], kOffL[2], vOffG[2], vOffL[2];
  #pragma unroll
  for (int i = 0; i < 2; i++) {
    int ci = i * 256 + t;
    int rK = ci >> 3, cK = ci & 7;
    kOffG[i] = rK * 64 + cK * 8;
    kOffL[i] = rK * 64 + ((cK ^ (rK & 7)) * 8);
    int rV = ci >> 3, c8 = ci & 7;
    int kb = c8 >> 2, cc = c8 & 3;
    vOffG[i] = rV * 2048 + c8 * 8;
    // key kb*32 + 16h+4a+b  ->  pos kb*32 + 8a+4h+b  (matches PV A-operand element order)
    vOffL[i] = rV * 72 + kb * 32 + 16 * (cc & 1) + 4 * (cc >> 1);
  }

  uint4 gk[2], gv[2];
  #pragma unroll
  for (int i = 0; i < 2; i++) gk[i] = *(const uint4*)(Kb + kOffG[i]);
  #pragma unroll
  for (int i = 0; i < 2; i++) gv[i] = *(const uint4*)(Vb + vOffG[i]);
  #pragma unroll
  for (int i = 0; i < 2; i++) *(uint4*)(&lKs[0][kOffL[i]]) = gk[i];
  #pragma unroll
  for (int i = 0; i < 2; i++) {
    uint2 lo; lo.x = gv[i].x; lo.y = gv[i].y;
    uint2 hi; hi.x = gv[i].z; hi.y = gv[i].w;
    *(uint2*)(&lVs[0][vOffL[i]]) = lo;
    *(uint2*)(&lVs[0][vOffL[i] + 8]) = hi;
  }
  __syncthreads();

  for (int tt = 0; tt < 32; ++tt) {
    const u16* lKc = lKs[tt & 1];
    const u16* lVc = lVs[tt & 1];
    if (tt < 31) {   // T14: issue next-tile global loads before compute
      #pragma unroll
      for (int i = 0; i < 2; i++) gk[i] = *(const uint4*)(Kb + (tt + 1) * 4096 + kOffG[i]);
      #pragma unroll
      for (int i = 0; i < 2; i++) gv[i] = *(const uint4*)(Vb + (tt + 1) * 64 + vOffG[i]);
    }
    __builtin_amdgcn_s_setprio(1);
    #pragma unroll
    for (int kb = 0; kb < 2; kb++) {
      const int sw = r16 & 7;
      const u16* kp0 = lKc + (kb * 32 + r16) * 64;
      const u16* kp1 = lKc + (kb * 32 + 16 + r16) * 64;
      bf16x8 kf00 = *(const bf16x8*)(kp0 + ((g ^ sw) * 8));
      bf16x8 kf01 = *(const bf16x8*)(kp0 + (((4 + g) ^ sw) * 8));
      bf16x8 kf10 = *(const bf16x8*)(kp1 + ((g ^ sw) * 8));
      bf16x8 kf11 = *(const bf16x8*)(kp1 + (((4 + g) ^ sw) * 8));
      bf16x8 vf[4];
      #pragma unroll
      for (int tdv = 0; tdv < 4; tdv++)
        vf[tdv] = *(const bf16x8*)(lVc + (tdv * 16 + r16) * 72 + kb * 32 + g * 8);
      #pragma unroll
      for (int j = 0; j < 2; j++) {
        f32x4 z0 = mma(kf00, qf[j][0], INIT4);
        z0 = mma(kf01, qf[j][1], z0);
        f32x4 z1 = mma(kf10, qf[j][0], INIT4);
        z1 = mma(kf11, qf[j][1], z1);
        float e0 = __builtin_amdgcn_exp2f(z0[0]), e1 = __builtin_amdgcn_exp2f(z0[1]);
        float e2 = __builtin_amdgcn_exp2f(z0[2]), e3 = __builtin_amdgcn_exp2f(z0[3]);
        float e4 = __builtin_amdgcn_exp2f(z1[0]), e5 = __builtin_amdgcn_exp2f(z1[1]);
        float e6 = __builtin_amdgcn_exp2f(z1[2]), e7 = __builtin_amdgcn_exp2f(z1[3]);
        u32x4 w_;
        w_.x = pk2(e0, e1); w_.y = pk2(e2, e3);
        w_.z = pk2(e4, e5); w_.w = pk2(e6, e7);
        bf16x8 pa = __builtin_bit_cast(bf16x8, w_);
        #pragma unroll
        for (int tdv = 0; tdv < 4; tdv++)
          o[j][tdv] = mma(pa, vf[tdv], o[j][tdv]);
        lsum[j] = mma(pa, ones, lsum[j]);
      }
    }
    __builtin_amdgcn_s_setprio(0);
    if (tt < 31) {   // write tile tt+1 into the other buffer (no reader conflict)
      u16* lKn = lKs[(tt + 1) & 1];
      u16* lVn = lVs[(tt + 1) & 1];
      #pragma unroll
      for (int i = 0; i < 2; i++) *(uint4*)(&lKn[kOffL[i]]) = gk[i];
      #pragma unroll
      for (int i = 0; i < 2; i++) {
        uint2 lo; lo.x = gv[i].x; lo.y = gv[i].y;
        uint2 hi; hi.x = gv[i].z; hi.y = gv[i].w;
        *(uint2*)(&lVn[vOffL[i]]) = lo;
        *(uint2*)(&lVn[vOffL[i] + 8]) = hi;
      }
    }
    __syncthreads();
  }

  #pragma unroll
  for (int j = 0; j < 2; j++) {
    f32x4 li;
    #pragma unroll
    for (int rg = 0; rg < 4; rg++) li[rg] = 1.0f / lsum[j][rg];
    #pragma unroll
    for (int tdv = 0; tdv < 4; tdv++)
      #pragma unroll
      for (int rg = 0; rg < 4; rg++) {
        int s = q0 + j * 16 + g * 4 + rg;
        ctx[((b * 2048 + s) * 1024) + h * 64 + tdv * 16 + r16] = f2bf(o[j][tdv][rg] * li[rg]);
      }
  }
}

// ---------------- output projection ----------------
__global__ __launch_bounds__(256) void k_gemm_proj(const u16* __restrict__ ctx,
                                                   const u16* __restrict__ pwb,
                                                   const float* __restrict__ pb,
                                                   float* __restrict__ out) {
  __shared__ __align__(16) u16 lds[16384];     // lA=lds[0..8191], lB=lds[8192..16383]
  f32x4 acc[4][4] = {};
  // XCD-chunked swizzle: 512 blocks -> 8 chunks of 8bm x 8bn
  int bid = blockIdx.y * 64 + blockIdx.x;
  int xcd = bid & 7, i0 = bid >> 3;
  int bx = xcd * 8 + (i0 >> 3);
  int by = i0 & 7;
  const int bm = bx * 128, bn = by * 128;
  gemm128(ctx, pwb, lds, lds + 8192, bm, bn, acc);
  const int lane = threadIdx.x & 63, wave = threadIdx.x >> 6;
  const int wr = wave >> 1, wc = wave & 1;
  const int g = lane >> 4, r16 = lane & 15;
  #pragma unroll
  for (int nj = 0; nj < 4; nj++) {
    int col = bn + wc * 64 + nj * 16 + r16;
    float bias = pb[col];
    #pragma unroll
    for (int mi = 0; mi < 4; mi++) {
      int mb = bm + wr * 64 + mi * 16 + g * 4;
      #pragma unroll
      for (int rg = 0; rg < 4; rg++)
        out[(mb + rg) * 1024 + col] = acc[mi][nj][rg] + bias;
    }
  }
}

extern "C" void kernel_launch(void* const* d_in, const int* in_sizes, int n_in,
                              void* d_out, int out_size, void* d_ws, size_t ws_size,
                              hipStream_t stream) {
  const float* x      = (const float*)d_in[0];
  const float* qkv_w  = (const float*)d_in[1];
  const float* qkv_b  = (const float*)d_in[2];
  const float* proj_w = (const float*)d_in[3];
  const float* proj_b = (const float*)d_in[4];
  float* out = (float*)d_out;
  char* ws = (char*)d_ws;

  u16* xb  = (u16*)(ws);                 // [8192][1024]
  u16* wb  = (u16*)(ws + 16777216);      // [3072][1024]
  u16* pwb = (u16*)(ws + 23068672);      // [1024][1024]
  u16* Qs  = (u16*)(ws + 25165824);      // Q*SCL2      [64][2048][64]
  u16* Ks  = (u16*)(ws + 41943040);      // K           [64][2048][64]
  u16* Vt  = (u16*)(ws + 58720256);      // V^T         [64][64][2048]
  u16* ctx = (u16*)(ws + 75497472);      // attn out    [8192][1024]

  cvt_all<<<2048, 256, 0, stream>>>(x, qkv_w, proj_w, (u16*)ws);
  k_gemm_qkv<<<dim3(64, 24), 256, 0, stream>>>(xb, wb, qkv_b, Qs, Ks, Vt);
  k_attn<<<1024, 256, 0, stream>>>(Qs, Ks, Vt, ctx);
  k_gemm_proj<<<dim3(64, 8), 256, 0, stream>>>(ctx, pwb, proj_b, out);
}

// Round 17
// 166.082 us; speedup vs baseline: 2.2427x; 1.0347x over previous
//
#include <hip/hip_runtime.h>
#include <stdint.h>

typedef float f32x4 __attribute__((ext_vector_type(4)));
typedef short bf16x8 __attribute__((ext_vector_type(8)));
typedef unsigned int u32x4 __attribute__((ext_vector_type(4)));
typedef unsigned short u16;
typedef unsigned int u32;

#define SCL2 0.1803368801111243f   // 0.125 * log2(e)

static __device__ __forceinline__ u16 f2bf(float f) {
  union { float f; u32 u; } x; x.f = f;
  return (u16)((x.u + 0x7FFFu + ((x.u >> 16) & 1u)) >> 16);  // RNE
}

static __device__ __forceinline__ u32 pk2(float lo, float hi) {
  u32 r;
  asm("v_cvt_pk_bf16_f32 %0, %1, %2" : "=v"(r) : "v"(lo), "v"(hi));
  return r;
}

static __device__ __forceinline__ f32x4 mma(bf16x8 a, bf16x8 b, f32x4 c) {
  return __builtin_amdgcn_mfma_f32_16x16x32_bf16(a, b, c, 0, 0, 0);
}

// async global->LDS DMA, 16B per lane; LDS dest is wave-uniform base + lane*16
static __device__ __forceinline__ void gl_lds16(const u16* g, u16* l) {
  __builtin_amdgcn_global_load_lds((const __attribute__((address_space(1))) void*)g,
                                   (__attribute__((address_space(3))) void*)l, 16, 0, 0);
}

// ---------------- fused f32 -> bf16 convert of x, qkv_w, proj_w (dests contiguous in ws) ----------------
__global__ __launch_bounds__(256) void cvt_all(const float* __restrict__ x,
                                               const float* __restrict__ w1,
                                               const float* __restrict__ w2,
                                               u16* __restrict__ dst) {
  int i = blockIdx.x * blockDim.x + threadIdx.x;
  int stride = gridDim.x * blockDim.x;
  for (; i < 3145728; i += stride) {           // total float4 count (x 2097152 | w1 786432 | w2 262144)
    const float4* src;
    int off;
    if (i < 2097152)      { src = (const float4*)x;  off = i; }
    else if (i < 2883584) { src = (const float4*)w1; off = i - 2097152; }
    else                  { src = (const float4*)w2; off = i - 2883584; }
    float4 v = src[off];
    ushort4 o;
    o.x = f2bf(v.x); o.y = f2bf(v.y); o.z = f2bf(v.z); o.w = f2bf(v.w);
    ((ushort4*)dst)[i] = o;
  }
}

// ---------------- shared 128x128x(K=1024) bf16 GEMM core: C = A * B^T ----------------
// m97-pattern staging: global_load_lds width=16 into LINEAR [128][64] LDS tiles, with
// pre-swizzled global source (srcChunk = c8 ^ (row&7)) and the same XOR on b128 frag reads.
static __device__ __forceinline__ void gemm128(const u16* __restrict__ A,
                                               const u16* __restrict__ Bmat,
                                               u16* lA, u16* lB,
                                               int bm, int bn, f32x4 (&acc)[4][4]) {
  const int t = threadIdx.x;
  const int lane = t & 63, wave = t >> 6;
  const int wr = wave >> 1, wc = wave & 1;
  const int g = lane >> 4, r16 = lane & 15;
  const int sw = r16 & 7;
  // staging geometry: call i covers rows i*32 + wave*8 + (lane>>3), src col chunk (lane&7)^(lane>>3)
  const int srow = wave * 8 + (lane >> 3);
  const int scol = ((lane & 7) ^ (lane >> 3)) * 8;
  const u16* As = A + (bm + srow) * 1024 + scol;
  const u16* Bs = Bmat + (bn + srow) * 1024 + scol;
  u16* const dA = lA + wave * 512;             // wave-uniform LDS base (elements)
  u16* const dB = lB + wave * 512;

  for (int kt = 0; kt < 1024; kt += 64) {
    __syncthreads();                           // all waves done reading previous tile
    #pragma unroll
    for (int i = 0; i < 4; i++) {
      gl_lds16(As + kt + i * 32768, dA + i * 2048);
      gl_lds16(Bs + kt + i * 32768, dB + i * 2048);
    }
    __syncthreads();                           // compiler drains vmcnt(0) before this barrier
    #pragma unroll
    for (int kk = 0; kk < 2; kk++) {
      bf16x8 af[4], bfr[4];
      #pragma unroll
      for (int mi = 0; mi < 4; mi++)
        af[mi] = *(const bf16x8*)(lA + (wr * 64 + mi * 16 + r16) * 64 + (((kk * 4 + g) ^ sw) * 8));
      #pragma unroll
      for (int nj = 0; nj < 4; nj++)
        bfr[nj] = *(const bf16x8*)(lB + (wc * 64 + nj * 16 + r16) * 64 + (((kk * 4 + g) ^ sw) * 8));
      #pragma unroll
      for (int mi = 0; mi < 4; mi++)
        #pragma unroll
        for (int nj = 0; nj < 4; nj++)
          acc[mi][nj] = mma(af[mi], bfr[nj], acc[mi][nj]);
    }
  }
}

// ---------------- QKV projection + scatter to per-head Q,K,V2 (bf16) ----------------
// Vt2 layout: [bh][tile(32)][dv(64)][chunk(8)x8elem]; content at (dv,chunk) = pos-chunk
// p = chunk ^ (dv&7); pos = kb*32 + 8a + 4h + b for key = kb*32 + 16h + 4a + b.
__global__ __launch_bounds__(256) void k_gemm_qkv(const u16* __restrict__ xb,
                                                  const u16* __restrict__ wb,
                                                  const float* __restrict__ qkv_b,
                                                  u16* __restrict__ Qs,
                                                  u16* __restrict__ Ks,
                                                  u16* __restrict__ Vt) {
  __shared__ __align__(16) u16 lds[18432];     // GEMM: lA=lds[0..8191], lB=lds[8192..16383]; V-epi needs 18432
  f32x4 acc[4][4] = {};
  // XCD-chunked swizzle: 1536 blocks -> 8 chunks of 16bm x 12bn
  int bid = blockIdx.y * 64 + blockIdx.x;
  int xcd = bid & 7, i0 = bid >> 3;
  int bx = (xcd >> 1) * 16 + i0 / 12;
  int by = (xcd & 1) * 12 + i0 % 12;
  const int bm = bx * 128, bn = by * 128;
  gemm128(xb, wb, lds, lds + 8192, bm, bn, acc);
  const int t = threadIdx.x, lane = t & 63, wave = t >> 6;
  const int wr = wave >> 1, wc = wave & 1;
  const int g = lane >> 4, r16 = lane & 15;
  if (bn < 2048) {
    // Q/K blocks
    #pragma unroll
    for (int nj = 0; nj < 4; nj++) {
      int f = bn + wc * 64 + nj * 16 + r16;
      float bias = qkv_b[f];
      int which = f >> 10;                      // 0=q 1=k
      int fl = f & 1023;
      int h = fl >> 6, dd = fl & 63;
      u16* base = which ? Ks : Qs;
      float scl = which ? 1.f : SCL2;
      #pragma unroll
      for (int mi = 0; mi < 4; mi++) {
        int mb = bm + wr * 64 + mi * 16 + g * 4;
        #pragma unroll
        for (int rg = 0; rg < 4; rg++) {
          int m = mb + rg;
          int b = m >> 11, s = m & 2047;
          base[(((b * 16 + h) * 2048) + s) * 64 + dd] = f2bf((acc[mi][nj][rg] + bias) * scl);
        }
      }
    }
  } else {
    // V blocks: transpose via LDS, then store in Vt2 pre-permuted pre-swizzled layout
    __syncthreads();
    #pragma unroll
    for (int nj = 0; nj < 4; nj++) {
      int fl = wc * 64 + nj * 16 + r16;         // 0..127
      float bias = qkv_b[bn + fl];
      #pragma unroll
      for (int mi = 0; mi < 4; mi++) {
        int ml = wr * 64 + mi * 16 + g * 4;
        *(u32*)(lds + fl * 144 + ml)     = pk2(acc[mi][nj][0] + bias, acc[mi][nj][1] + bias);
        *(u32*)(lds + fl * 144 + ml + 2) = pk2(acc[mi][nj][2] + bias, acc[mi][nj][3] + bias);
      }
    }
    __syncthreads();
    int b = bm >> 11, s0 = bm & 2047;
    #pragma unroll
    for (int i = 0; i < 8; i++) {
      int fl = i * 16 + (t >> 4);
      int m8 = (t & 15) * 8;
      uint4 val = *(uint4*)(lds + fl * 144 + m8);   // 8 consecutive keys K0..K0+7, feature fl
      int f = bn + fl - 2048;
      int hd = f >> 6, dv = f & 63;
      int bh2 = b * 16 + hd;
      int K0 = s0 + m8;
      int tt = K0 >> 6, key64 = K0 & 63;
      int kb2 = key64 >> 5, o = key64 & 31;
      int ph = o >> 4;                               // h of pos formula
      int a0 = (o & 15) >> 2;                        // 0 or 2
      int base2 = ((bh2 * 32 + tt) * 64 + dv) * 64 + 4 * ph;
      uint2 lo; lo.x = val.x; lo.y = val.y;          // keys K0..K0+3 (a = a0)
      uint2 hi; hi.x = val.z; hi.y = val.w;          // keys K0+4..K0+7 (a = a0+1)
      *(uint2*)(Vt + base2 + (((kb2 * 4 + a0)     ^ (dv & 7)) * 8)) = lo;
      *(uint2*)(Vt + base2 + (((kb2 * 4 + a0 + 1) ^ (dv & 7)) * 8)) = hi;
    }
  }
}

// ---------------- flash attention v12: v9 math + DMA-staged K/V (linear LDS, swizzled src) ----------------
__global__ __launch_bounds__(256, 4) void k_attn(const u16* __restrict__ Qs,
                                                 const u16* __restrict__ Ks,
                                                 const u16* __restrict__ Vt,
                                                 u16* __restrict__ ctx) {
  __shared__ __align__(16) u16 lKs[2][4096];   // K tiles [64 key][64 d], src-swizzled, 8 KiB each
  __shared__ __align__(16) u16 lVs[2][4096];   // V tiles [64 dv][64 pos], pre-permuted in Vt2, 8 KiB each
  // flat 1024 blocks; XCD x owns lin [x*128, x*128+128) = bh x*8..x*8+7 (all 16 qt each)
  int bid = blockIdx.x;
  int lin = (bid & 7) * 128 + (bid >> 3);
  const int bh = lin >> 4, qt = lin & 15;
  const int b = bh >> 4, h = bh & 15;
  const u16* Qb = Qs + bh * (2048 * 64);
  const u16* Kb = Ks + bh * (2048 * 64);
  const u16* Vb = Vt + bh * (32 * 4096);       // Vt2 per-bh base
  const int t = threadIdx.x, lane = t & 63, wave = t >> 6;
  const int g = lane >> 4, r16 = lane & 15;
  const int q0 = qt * 128 + wave * 32;

  // Q fragments (B-operand of swapped QK^T), k = kk*32 + g*8 + i
  bf16x8 qf[2][2];
  #pragma unroll
  for (int j = 0; j < 2; j++)
    #pragma unroll
    for (int kk = 0; kk < 2; kk++)
      qf[j][kk] = *(const bf16x8*)(Qb + (q0 + j * 16 + r16) * 64 + kk * 32 + g * 8);

  u32x4 onesw;
  onesw.x = 0x3F803F80u; onesw.y = 0x3F803F80u; onesw.z = 0x3F803F80u; onesw.w = 0x3F803F80u;
  const bf16x8 ones = __builtin_bit_cast(bf16x8, onesw);

  f32x4 o[2][4] = {};
  f32x4 lsum[2] = {};
  const f32x4 INIT4 = {-4.f, -4.f, -4.f, -4.f};  // fixed softmax max (log2), cancels in ratio

  // staging geometry: call i covers 16B chunks ci = i*256 + t; dest = linear LDS
  int kSrc[2], vSrc[2], dOff[2];
  #pragma unroll
  for (int i = 0; i < 2; i++) {
    int ci = i * 256 + t;
    int rK = ci >> 3, c8 = ci & 7;
    kSrc[i] = rK * 64 + ((c8 ^ (rK & 7)) * 8);   // pre-swizzled K source
    vSrc[i] = ci * 8;                             // V fully linear (swizzle baked into Vt2)
    dOff[i] = i * 2048 + wave * 512;              // wave-uniform LDS base (elements)
  }

  // prologue: DMA tile 0 into buffer 0
  #pragma unroll
  for (int i = 0; i < 2; i++) {
    gl_lds16(Kb + kSrc[i], &lKs[0][dOff[i]]);
    gl_lds16(Vb + vSrc[i], &lVs[0][dOff[i]]);
  }
  __syncthreads();

  for (int tt = 0; tt < 32; ++tt) {
    const u16* lKc = lKs[tt & 1];
    const u16* lVc = lVs[tt & 1];
    if (tt < 31) {   // DMA next tile into the other buffer; lands during compute
      const u16* Ksrc = Kb + (tt + 1) * 4096;
      const u16* Vsrc = Vb + (tt + 1) * 4096;
      u16* dK = lKs[(tt + 1) & 1];
      u16* dV = lVs[(tt + 1) & 1];
      #pragma unroll
      for (int i = 0; i < 2; i++) {
        gl_lds16(Ksrc + kSrc[i], dK + dOff[i]);
        gl_lds16(Vsrc + vSrc[i], dV + dOff[i]);
      }
    }
    __builtin_amdgcn_s_setprio(1);
    #pragma unroll
    for (int kb = 0; kb < 2; kb++) {
      const int sw = r16 & 7;
      const u16* kp0 = lKc + (kb * 32 + r16) * 64;
      const u16* kp1 = lKc + (kb * 32 + 16 + r16) * 64;
      bf16x8 kf00 = *(const bf16x8*)(kp0 + ((g ^ sw) * 8));
      bf16x8 kf01 = *(const bf16x8*)(kp0 + (((4 + g) ^ sw) * 8));
      bf16x8 kf10 = *(const bf16x8*)(kp1 + ((g ^ sw) * 8));
      bf16x8 kf11 = *(const bf16x8*)(kp1 + (((4 + g) ^ sw) * 8));
      bf16x8 vf[4];
      #pragma unroll
      for (int tdv = 0; tdv < 4; tdv++)
        vf[tdv] = *(const bf16x8*)(lVc + (tdv * 16 + r16) * 64 + (((kb * 4 + g) ^ sw) * 8));
      #pragma unroll
      for (int j = 0; j < 2; j++) {
        f32x4 z0 = mma(kf00, qf[j][0], INIT4);
        z0 = mma(kf01, qf[j][1], z0);
        f32x4 z1 = mma(kf10, qf[j][0], INIT4);
        z1 = mma(kf11, qf[j][1], z1);
        float e0 = __builtin_amdgcn_exp2f(z0[0]), e1 = __builtin_amdgcn_exp2f(z0[1]);
        float e2 = __builtin_amdgcn_exp2f(z0[2]), e3 = __builtin_amdgcn_exp2f(z0[3]);
        float e4 = __builtin_amdgcn_exp2f(z1[0]), e5 = __builtin_amdgcn_exp2f(z1[1]);
        float e6 = __builtin_amdgcn_exp2f(z1[2]), e7 = __builtin_amdgcn_exp2f(z1[3]);
        u32x4 w_;
        w_.x = pk2(e0, e1); w_.y = pk2(e2, e3);
        w_.z = pk2(e4, e5); w_.w = pk2(e6, e7);
        bf16x8 pa = __builtin_bit_cast(bf16x8, w_);
        #pragma unroll
        for (int tdv = 0; tdv < 4; tdv++)
          o[j][tdv] = mma(pa, vf[tdv], o[j][tdv]);
        lsum[j] = mma(pa, ones, lsum[j]);
      }
    }
    __builtin_amdgcn_s_setprio(0);
    __syncthreads();   // compiler drains vmcnt before barrier -> next tile's DMA complete
  }

  #pragma unroll
  for (int j = 0; j < 2; j++) {
    f32x4 li;
    #pragma unroll
    for (int rg = 0; rg < 4; rg++) li[rg] = 1.0f / lsum[j][rg];
    #pragma unroll
    for (int tdv = 0; tdv < 4; tdv++)
      #pragma unroll
      for (int rg = 0; rg < 4; rg++) {
        int s = q0 + j * 16 + g * 4 + rg;
        ctx[((b * 2048 + s) * 1024) + h * 64 + tdv * 16 + r16] = f2bf(o[j][tdv][rg] * li[rg]);
      }
  }
}

// ---------------- output projection ----------------
__global__ __launch_bounds__(256) void k_gemm_proj(const u16* __restrict__ ctx,
                                                   const u16* __restrict__ pwb,
                                                   const float* __restrict__ pb,
                                                   float* __restrict__ out) {
  __shared__ __align__(16) u16 lds[16384];     // lA=lds[0..8191], lB=lds[8192..16383]
  f32x4 acc[4][4] = {};
  // XCD-chunked swizzle: 512 blocks -> 8 chunks of 8bm x 8bn
  int bid = blockIdx.y * 64 + blockIdx.x;
  int xcd = bid & 7, i0 = bid >> 3;
  int bx = xcd * 8 + (i0 >> 3);
  int by = i0 & 7;
  const int bm = bx * 128, bn = by * 128;
  gemm128(ctx, pwb, lds, lds + 8192, bm, bn, acc);
  const int lane = threadIdx.x & 63, wave = threadIdx.x >> 6;
  const int wr = wave >> 1, wc = wave & 1;
  const int g = lane >> 4, r16 = lane & 15;
  #pragma unroll
  for (int nj = 0; nj < 4; nj++) {
    int col = bn + wc * 64 + nj * 16 + r16;
    float bias = pb[col];
    #pragma unroll
    for (int mi = 0; mi < 4; mi++) {
      int mb = bm + wr * 64 + mi * 16 + g * 4;
      #pragma unroll
      for (int rg = 0; rg < 4; rg++)
        out[(mb + rg) * 1024 + col] = acc[mi][nj][rg] + bias;
    }
  }
}

extern "C" void kernel_launch(void* const* d_in, const int* in_sizes, int n_in,
                              void* d_out, int out_size, void* d_ws, size_t ws_size,
                              hipStream_t stream) {
  const float* x      = (const float*)d_in[0];
  const float* qkv_w  = (const float*)d_in[1];
  const float* qkv_b  = (const float*)d_in[2];
  const float* proj_w = (const float*)d_in[3];
  const float* proj_b = (const float*)d_in[4];
  float* out = (float*)d_out;
  char* ws = (char*)d_ws;

  u16* xb  = (u16*)(ws);                 // [8192][1024]
  u16* wb  = (u16*)(ws + 16777216);      // [3072][1024]
  u16* pwb = (u16*)(ws + 23068672);      // [1024][1024]
  u16* Qs  = (u16*)(ws + 25165824);      // Q*SCL2      [64][2048][64]
  u16* Ks  = (u16*)(ws + 41943040);      // K           [64][2048][64]
  u16* Vt  = (u16*)(ws + 58720256);      // V2 pre-permuted [64][32][64][64]
  u16* ctx = (u16*)(ws + 75497472);      // attn out    [8192][1024]

  cvt_all<<<2048, 256, 0, stream>>>(x, qkv_w, proj_w, (u16*)ws);
  k_gemm_qkv<<<dim3(64, 24), 256, 0, stream>>>(xb, wb, qkv_b, Qs, Ks, Vt);
  k_attn<<<1024, 256, 0, stream>>>(Qs, Ks, Vt, ctx);
  k_gemm_proj<<<dim3(64, 8), 256, 0, stream>>>(ctx, pwb, proj_b, out);
}

// Round 18
// 164.563 us; speedup vs baseline: 2.2634x; 1.0092x over previous
//
#include <hip/hip_runtime.h>
#include <stdint.h>

typedef float f32x4 __attribute__((ext_vector_type(4)));
typedef short bf16x8 __attribute__((ext_vector_type(8)));
typedef unsigned int u32x4 __attribute__((ext_vector_type(4)));
typedef unsigned short u16;
typedef unsigned int u32;

#define SCL2 0.1803368801111243f   // 0.125 * log2(e)

static __device__ __forceinline__ u16 f2bf(float f) {
  union { float f; u32 u; } x; x.f = f;
  return (u16)((x.u + 0x7FFFu + ((x.u >> 16) & 1u)) >> 16);  // RNE
}

static __device__ __forceinline__ u32 pk2(float lo, float hi) {
  u32 r;
  asm("v_cvt_pk_bf16_f32 %0, %1, %2" : "=v"(r) : "v"(lo), "v"(hi));
  return r;
}

static __device__ __forceinline__ f32x4 mma(bf16x8 a, bf16x8 b, f32x4 c) {
  return __builtin_amdgcn_mfma_f32_16x16x32_bf16(a, b, c, 0, 0, 0);
}

// async global->LDS DMA, 16B per lane; LDS dest is wave-uniform base + lane*16
static __device__ __forceinline__ void gl_lds16(const u16* g, u16* l) {
  __builtin_amdgcn_global_load_lds((const __attribute__((address_space(1))) void*)g,
                                   (__attribute__((address_space(3))) void*)l, 16, 0, 0);
}

// ---------------- fused f32 -> bf16 convert of x, qkv_w, proj_w (dests contiguous in ws) ----------------
__global__ __launch_bounds__(256) void cvt_all(const float* __restrict__ x,
                                               const float* __restrict__ w1,
                                               const float* __restrict__ w2,
                                               u16* __restrict__ dst) {
  int i = blockIdx.x * blockDim.x + threadIdx.x;
  int stride = gridDim.x * blockDim.x;
  for (; i < 3145728; i += stride) {           // total float4 count (x 2097152 | w1 786432 | w2 262144)
    const float4* src;
    int off;
    if (i < 2097152)      { src = (const float4*)x;  off = i; }
    else if (i < 2883584) { src = (const float4*)w1; off = i - 2097152; }
    else                  { src = (const float4*)w2; off = i - 2883584; }
    float4 v = src[off];
    ushort4 o;
    o.x = f2bf(v.x); o.y = f2bf(v.y); o.z = f2bf(v.z); o.w = f2bf(v.w);
    ((ushort4*)dst)[i] = o;
  }
}

// ---------------- shared 128x128x(K=1024) bf16 GEMM core: C = A * B^T ----------------
// m97-pattern staging: global_load_lds width=16 into LINEAR [128][64] LDS tiles, with
// pre-swizzled global source (srcChunk = c8 ^ (row&7)) and the same XOR on b128 frag reads.
static __device__ __forceinline__ void gemm128(const u16* __restrict__ A,
                                               const u16* __restrict__ Bmat,
                                               u16* lA, u16* lB,
                                               int bm, int bn, f32x4 (&acc)[4][4]) {
  const int t = threadIdx.x;
  const int lane = t & 63, wave = t >> 6;
  const int wr = wave >> 1, wc = wave & 1;
  const int g = lane >> 4, r16 = lane & 15;
  const int sw = r16 & 7;
  // staging geometry: call i covers rows i*32 + wave*8 + (lane>>3), src col chunk (lane&7)^(lane>>3)
  const int srow = wave * 8 + (lane >> 3);
  const int scol = ((lane & 7) ^ (lane >> 3)) * 8;
  const u16* As = A + (bm + srow) * 1024 + scol;
  const u16* Bs = Bmat + (bn + srow) * 1024 + scol;
  u16* const dA = lA + wave * 512;             // wave-uniform LDS base (elements)
  u16* const dB = lB + wave * 512;

  for (int kt = 0; kt < 1024; kt += 64) {
    __syncthreads();                           // all waves done reading previous tile
    #pragma unroll
    for (int i = 0; i < 4; i++) {
      gl_lds16(As + kt + i * 32768, dA + i * 2048);
      gl_lds16(Bs + kt + i * 32768, dB + i * 2048);
    }
    __syncthreads();                           // compiler drains vmcnt(0) before this barrier
    #pragma unroll
    for (int kk = 0; kk < 2; kk++) {
      bf16x8 af[4], bfr[4];
      #pragma unroll
      for (int mi = 0; mi < 4; mi++)
        af[mi] = *(const bf16x8*)(lA + (wr * 64 + mi * 16 + r16) * 64 + (((kk * 4 + g) ^ sw) * 8));
      #pragma unroll
      for (int nj = 0; nj < 4; nj++)
        bfr[nj] = *(const bf16x8*)(lB + (wc * 64 + nj * 16 + r16) * 64 + (((kk * 4 + g) ^ sw) * 8));
      #pragma unroll
      for (int mi = 0; mi < 4; mi++)
        #pragma unroll
        for (int nj = 0; nj < 4; nj++)
          acc[mi][nj] = mma(af[mi], bfr[nj], acc[mi][nj]);
    }
  }
}

// ---------------- QKV projection + scatter to per-head Q,K,V2 (bf16) ----------------
// Vt2 layout: [bh][tile(32)][dv(64)][64 elems]; chunk c holds pos-chunk p = c ^ (dv&7):
// intra j -> key64 = kb*32 + 16*(j>>2) + 4a + (j&3), kb = p>>2, a = p&3.
__global__ __launch_bounds__(256) void k_gemm_qkv(const u16* __restrict__ xb,
                                                  const u16* __restrict__ wb,
                                                  const float* __restrict__ qkv_b,
                                                  u16* __restrict__ Qs,
                                                  u16* __restrict__ Ks,
                                                  u16* __restrict__ Vt) {
  __shared__ __align__(16) u16 lds[18432];     // GEMM: lA=lds[0..8191], lB=lds[8192..16383]; V-epi needs 18432
  f32x4 acc[4][4] = {};
  // XCD-chunked swizzle: 1536 blocks -> 8 chunks of 16bm x 12bn
  int bid = blockIdx.y * 64 + blockIdx.x;
  int xcd = bid & 7, i0 = bid >> 3;
  int bx = (xcd >> 1) * 16 + i0 / 12;
  int by = (xcd & 1) * 12 + i0 % 12;
  const int bm = bx * 128, bn = by * 128;
  gemm128(xb, wb, lds, lds + 8192, bm, bn, acc);
  const int t = threadIdx.x, lane = t & 63, wave = t >> 6;
  const int wr = wave >> 1, wc = wave & 1;
  const int g = lane >> 4, r16 = lane & 15;
  if (bn < 2048) {
    // Q/K blocks
    #pragma unroll
    for (int nj = 0; nj < 4; nj++) {
      int f = bn + wc * 64 + nj * 16 + r16;
      float bias = qkv_b[f];
      int which = f >> 10;                      // 0=q 1=k
      int fl = f & 1023;
      int h = fl >> 6, dd = fl & 63;
      u16* base = which ? Ks : Qs;
      float scl = which ? 1.f : SCL2;
      #pragma unroll
      for (int mi = 0; mi < 4; mi++) {
        int mb = bm + wr * 64 + mi * 16 + g * 4;
        #pragma unroll
        for (int rg = 0; rg < 4; rg++) {
          int m = mb + rg;
          int b = m >> 11, s = m & 2047;
          base[(((b * 16 + h) * 2048) + s) * 64 + dd] = f2bf((acc[mi][nj][rg] + bias) * scl);
        }
      }
    }
  } else {
    // V blocks: transpose via LDS, then GATHER into Vt2 chunks -> fully coalesced 16B stores
    __syncthreads();
    #pragma unroll
    for (int nj = 0; nj < 4; nj++) {
      int fl = wc * 64 + nj * 16 + r16;         // 0..127
      float bias = qkv_b[bn + fl];
      #pragma unroll
      for (int mi = 0; mi < 4; mi++) {
        int ml = wr * 64 + mi * 16 + g * 4;
        *(u32*)(lds + fl * 144 + ml)     = pk2(acc[mi][nj][0] + bias, acc[mi][nj][1] + bias);
        *(u32*)(lds + fl * 144 + ml + 2) = pk2(acc[mi][nj][2] + bias, acc[mi][nj][3] + bias);
      }
    }
    __syncthreads();
    int b = bm >> 11;
    int tt0 = (bm & 2047) >> 6;                 // first of the 2 key-tiles this block covers
    int c = t & 7, dvq = t >> 3;                // chunk 0..7, dv-row 0..31
    #pragma unroll
    for (int i = 0; i < 8; i++) {               // 2 heads x 2 tiles x 2 dv-halves
      int hd = i >> 2, ti = (i >> 1) & 1, dv = (i & 1) * 32 + dvq;
      int fl = hd * 64 + dv;
      int p = c ^ (dv & 7);
      int kb = p >> 2, a = p & 3;
      const u16* src = lds + fl * 144 + ti * 64 + kb * 32 + 4 * a;
      uint2 lo = *(const uint2*)(src);          // keys kb*32+4a+0..3 (h=0)
      uint2 hi = *(const uint2*)(src + 16);     // keys kb*32+16+4a+0..3 (h=1)
      int f = bn - 2048 + fl;
      int bh2 = b * 16 + (f >> 6);
      uint4 val; val.x = lo.x; val.y = lo.y; val.z = hi.x; val.w = hi.y;
      *(uint4*)(Vt + (((bh2 * 32 + tt0 + ti) * 64 + dv) * 64) + c * 8) = val;
    }
  }
}

// ---------------- flash attention v12: v9 math + DMA-staged K/V (linear LDS, swizzled src) ----------------
__global__ __launch_bounds__(256, 4) void k_attn(const u16* __restrict__ Qs,
                                                 const u16* __restrict__ Ks,
                                                 const u16* __restrict__ Vt,
                                                 u16* __restrict__ ctx) {
  __shared__ __align__(16) u16 lKs[2][4096];   // K tiles [64 key][64 d], src-swizzled, 8 KiB each
  __shared__ __align__(16) u16 lVs[2][4096];   // V tiles [64 dv][64 pos], pre-permuted in Vt2, 8 KiB each
  // flat 1024 blocks; XCD x owns lin [x*128, x*128+128) = bh x*8..x*8+7 (all 16 qt each)
  int bid = blockIdx.x;
  int lin = (bid & 7) * 128 + (bid >> 3);
  const int bh = lin >> 4, qt = lin & 15;
  const int b = bh >> 4, h = bh & 15;
  const u16* Qb = Qs + bh * (2048 * 64);
  const u16* Kb = Ks + bh * (2048 * 64);
  const u16* Vb = Vt + bh * (32 * 4096);       // Vt2 per-bh base
  const int t = threadIdx.x, lane = t & 63, wave = t >> 6;
  const int g = lane >> 4, r16 = lane & 15;
  const int q0 = qt * 128 + wave * 32;

  // Q fragments (B-operand of swapped QK^T), k = kk*32 + g*8 + i
  bf16x8 qf[2][2];
  #pragma unroll
  for (int j = 0; j < 2; j++)
    #pragma unroll
    for (int kk = 0; kk < 2; kk++)
      qf[j][kk] = *(const bf16x8*)(Qb + (q0 + j * 16 + r16) * 64 + kk * 32 + g * 8);

  u32x4 onesw;
  onesw.x = 0x3F803F80u; onesw.y = 0x3F803F80u; onesw.z = 0x3F803F80u; onesw.w = 0x3F803F80u;
  const bf16x8 ones = __builtin_bit_cast(bf16x8, onesw);

  f32x4 o[2][4] = {};
  f32x4 lsum[2] = {};
  const f32x4 INIT4 = {-4.f, -4.f, -4.f, -4.f};  // fixed softmax max (log2), cancels in ratio

  // staging geometry: call i covers 16B chunks ci = i*256 + t; dest = linear LDS
  int kSrc[2], vSrc[2], dOff[2];
  #pragma unroll
  for (int i = 0; i < 2; i++) {
    int ci = i * 256 + t;
    int rK = ci >> 3, c8 = ci & 7;
    kSrc[i] = rK * 64 + ((c8 ^ (rK & 7)) * 8);   // pre-swizzled K source
    vSrc[i] = ci * 8;                             // V fully linear (swizzle baked into Vt2)
    dOff[i] = i * 2048 + wave * 512;              // wave-uniform LDS base (elements)
  }

  // prologue: DMA tile 0 into buffer 0
  #pragma unroll
  for (int i = 0; i < 2; i++) {
    gl_lds16(Kb + kSrc[i], &lKs[0][dOff[i]]);
    gl_lds16(Vb + vSrc[i], &lVs[0][dOff[i]]);
  }
  __syncthreads();

  for (int tt = 0; tt < 32; ++tt) {
    const u16* lKc = lKs[tt & 1];
    const u16* lVc = lVs[tt & 1];
    if (tt < 31) {   // DMA next tile into the other buffer; lands during compute
      const u16* Ksrc = Kb + (tt + 1) * 4096;
      const u16* Vsrc = Vb + (tt + 1) * 4096;
      u16* dK = lKs[(tt + 1) & 1];
      u16* dV = lVs[(tt + 1) & 1];
      #pragma unroll
      for (int i = 0; i < 2; i++) {
        gl_lds16(Ksrc + kSrc[i], dK + dOff[i]);
        gl_lds16(Vsrc + vSrc[i], dV + dOff[i]);
      }
    }
    __builtin_amdgcn_s_setprio(1);
    #pragma unroll
    for (int kb = 0; kb < 2; kb++) {
      const int sw = r16 & 7;
      const u16* kp0 = lKc + (kb * 32 + r16) * 64;
      const u16* kp1 = lKc + (kb * 32 + 16 + r16) * 64;
      bf16x8 kf00 = *(const bf16x8*)(kp0 + ((g ^ sw) * 8));
      bf16x8 kf01 = *(const bf16x8*)(kp0 + (((4 + g) ^ sw) * 8));
      bf16x8 kf10 = *(const bf16x8*)(kp1 + ((g ^ sw) * 8));
      bf16x8 kf11 = *(const bf16x8*)(kp1 + (((4 + g) ^ sw) * 8));
      bf16x8 vf[4];
      #pragma unroll
      for (int tdv = 0; tdv < 4; tdv++)
        vf[tdv] = *(const bf16x8*)(lVc + (tdv * 16 + r16) * 64 + (((kb * 4 + g) ^ sw) * 8));
      #pragma unroll
      for (int j = 0; j < 2; j++) {
        f32x4 z0 = mma(kf00, qf[j][0], INIT4);
        z0 = mma(kf01, qf[j][1], z0);
        f32x4 z1 = mma(kf10, qf[j][0], INIT4);
        z1 = mma(kf11, qf[j][1], z1);
        float e0 = __builtin_amdgcn_exp2f(z0[0]), e1 = __builtin_amdgcn_exp2f(z0[1]);
        float e2 = __builtin_amdgcn_exp2f(z0[2]), e3 = __builtin_amdgcn_exp2f(z0[3]);
        float e4 = __builtin_amdgcn_exp2f(z1[0]), e5 = __builtin_amdgcn_exp2f(z1[1]);
        float e6 = __builtin_amdgcn_exp2f(z1[2]), e7 = __builtin_amdgcn_exp2f(z1[3]);
        u32x4 w_;
        w_.x = pk2(e0, e1); w_.y = pk2(e2, e3);
        w_.z = pk2(e4, e5); w_.w = pk2(e6, e7);
        bf16x8 pa = __builtin_bit_cast(bf16x8, w_);
        #pragma unroll
        for (int tdv = 0; tdv < 4; tdv++)
          o[j][tdv] = mma(pa, vf[tdv], o[j][tdv]);
        lsum[j] = mma(pa, ones, lsum[j]);
      }
    }
    __builtin_amdgcn_s_setprio(0);
    __syncthreads();   // compiler drains vmcnt before barrier -> next tile's DMA complete
  }

  #pragma unroll
  for (int j = 0; j < 2; j++) {
    f32x4 li;
    #pragma unroll
    for (int rg = 0; rg < 4; rg++) li[rg] = 1.0f / lsum[j][rg];
    #pragma unroll
    for (int tdv = 0; tdv < 4; tdv++)
      #pragma unroll
      for (int rg = 0; rg < 4; rg++) {
        int s = q0 + j * 16 + g * 4 + rg;
        ctx[((b * 2048 + s) * 1024) + h * 64 + tdv * 16 + r16] = f2bf(o[j][tdv][rg] * li[rg]);
      }
  }
}

// ---------------- output projection ----------------
__global__ __launch_bounds__(256) void k_gemm_proj(const u16* __restrict__ ctx,
                                                   const u16* __restrict__ pwb,
                                                   const float* __restrict__ pb,
                                                   float* __restrict__ out) {
  __shared__ __align__(16) u16 lds[16384];     // lA=lds[0..8191], lB=lds[8192..16383]
  f32x4 acc[4][4] = {};
  // XCD-chunked swizzle: 512 blocks -> 8 chunks of 8bm x 8bn
  int bid = blockIdx.y * 64 + blockIdx.x;
  int xcd = bid & 7, i0 = bid >> 3;
  int bx = xcd * 8 + (i0 >> 3);
  int by = i0 & 7;
  const int bm = bx * 128, bn = by * 128;
  gemm128(ctx, pwb, lds, lds + 8192, bm, bn, acc);
  const int lane = threadIdx.x & 63, wave = threadIdx.x >> 6;
  const int wr = wave >> 1, wc = wave & 1;
  const int g = lane >> 4, r16 = lane & 15;
  #pragma unroll
  for (int nj = 0; nj < 4; nj++) {
    int col = bn + wc * 64 + nj * 16 + r16;
    float bias = pb[col];
    #pragma unroll
    for (int mi = 0; mi < 4; mi++) {
      int mb = bm + wr * 64 + mi * 16 + g * 4;
      #pragma unroll
      for (int rg = 0; rg < 4; rg++)
        out[(mb + rg) * 1024 + col] = acc[mi][nj][rg] + bias;
    }
  }
}

extern "C" void kernel_launch(void* const* d_in, const int* in_sizes, int n_in,
                              void* d_out, int out_size, void* d_ws, size_t ws_size,
                              hipStream_t stream) {
  const float* x      = (const float*)d_in[0];
  const float* qkv_w  = (const float*)d_in[1];
  const float* qkv_b  = (const float*)d_in[2];
  const float* proj_w = (const float*)d_in[3];
  const float* proj_b = (const float*)d_in[4];
  float* out = (float*)d_out;
  char* ws = (char*)d_ws;

  u16* xb  = (u16*)(ws);                 // [8192][1024]
  u16* wb  = (u16*)(ws + 16777216);      // [3072][1024]
  u16* pwb = (u16*)(ws + 23068672);      // [1024][1024]
  u16* Qs  = (u16*)(ws + 25165824);      // Q*SCL2      [64][2048][64]
  u16* Ks  = (u16*)(ws + 41943040);      // K           [64][2048][64]
  u16* Vt  = (u16*)(ws + 58720256);      // V2 pre-permuted [64][32][64][64]
  u16* ctx = (u16*)(ws + 75497472);      // attn out    [8192][1024]

  cvt_all<<<2048, 256, 0, stream>>>(x, qkv_w, proj_w, (u16*)ws);
  k_gemm_qkv<<<dim3(64, 24), 256, 0, stream>>>(xb, wb, qkv_b, Qs, Ks, Vt);
  k_attn<<<1024, 256, 0, stream>>>(Qs, Ks, Vt, ctx);
  k_gemm_proj<<<dim3(64, 8), 256, 0, stream>>>(ctx, pwb, proj_b, out);
}